// Round 1
// baseline (2332.932 us; speedup 1.0000x reference)
//
#include <hip/hip_runtime.h>

// ---------------- problem constants ----------------
#define NNODES 100000
#define NEDGES 1000000
#define NGRAPH 512
// dims: NN=128 node feats, NE=64 edge attr, H=256 hidden, OUT=128, EMB=64
// edge MLP K = 2*128+64+1 = 321 -> pad 352 ; node MLP K = 128+64+3 = 195 -> pad 224

typedef unsigned short u16;
typedef unsigned int u32;
typedef __attribute__((ext_vector_type(8))) __bf16 bf16x8;
typedef __attribute__((ext_vector_type(4))) float f32x4;

__device__ __forceinline__ u16 f2bf(float f) {
  u32 u = __builtin_bit_cast(u32, f);
  u += 0x7FFFu + ((u >> 16) & 1u);   // RNE
  return (u16)(u >> 16);
}
__device__ __forceinline__ float bf2f(u16 b) {
  u32 u = ((u32)b) << 16;
  return __builtin_bit_cast(float, u);
}
__device__ __forceinline__ u32 pk2(float a, float b) {
  return (u32)f2bf(a) | ((u32)f2bf(b) << 16);
}
__device__ __forceinline__ uint4 pack8(float4 lo, float4 hi) {
  return make_uint4(pk2(lo.x, lo.y), pk2(lo.z, lo.w), pk2(hi.x, hi.y), pk2(hi.z, hi.w));
}
__device__ __forceinline__ f32x4 mfma16(const u16* a, const u16* b, f32x4 c) {
  return __builtin_amdgcn_mfma_f32_16x16x32_bf16(
      *reinterpret_cast<const bf16x8*>(a),
      *reinterpret_cast<const bf16x8*>(b), c, 0, 0, 0);
}

// ---------------- workspace layout (bytes, all 16-aligned) ----------------
constexpr size_t OFF_NFBF   = 0;                          // u16 [1e5][128]  = 25,600,000
constexpr size_t OFF_W1ET   = OFF_NFBF   + 25600000;      // u16 [256][352]  = 180,224
constexpr size_t OFF_W2ET   = OFF_W1ET   + 180224;        // u16 [64][256]   = 32,768
constexpr size_t OFF_EEMBT  = OFF_W2ET   + 32768;         // u16 [64][64]    = 8,192
constexpr size_t OFF_W1NT   = OFF_EEMBT  + 8192;          // u16 [256][224]  = 114,688
constexpr size_t OFF_W2NT   = OFF_W1NT   + 114688;        // u16 [128][256]  = 65,536
constexpr size_t OFF_NEMBT  = OFF_W2NT   + 65536;         // u16 [64][128]   = 16,384
constexpr size_t OFF_COUNTS = OFF_NEMBT  + 16384;         // int [1e5]       = 400,000
constexpr size_t OFF_GCNT   = OFF_COUNTS + 400000;        // int [512]       = 2,048
constexpr size_t OFF_OFFS   = OFF_GCNT   + 2048;          // int [1e5+1]     -> 400,016
constexpr size_t OFF_GOFFS  = OFF_OFFS   + 400016;        // int [513]       -> 2,064
constexpr size_t OFF_CURSOR = OFF_GOFFS  + 2064;          // int [1e5]       = 400,000
constexpr size_t OFF_CSR    = OFF_CURSOR + 400000;        // int [1e6]       = 4,000,000
constexpr size_t OFF_EOUT   = OFF_CSR    + 4000000;       // u16 [1e6][64]   = 128,000,000
constexpr size_t OFF_TRANS  = OFF_EOUT   + 128000000;     // f32 [1e6][3]    = 12,000,000
constexpr size_t OFF_AGG    = OFF_TRANS  + 12000000;      // f32 [1e5][64]   = 25,600,000

// ---------------- prep kernels ----------------
__global__ __launch_bounds__(256) void k_prep_nf(const float* __restrict__ in,
                                                 u16* __restrict__ out) {
  int i = blockIdx.x * 256 + threadIdx.x;  // 1,600,000 groups of 8 elems (exact)
  const float4* p = reinterpret_cast<const float4*>(in) + (size_t)i * 2;
  reinterpret_cast<uint4*>(out)[i] = pack8(p[0], p[1]);
}

__global__ __launch_bounds__(256) void k_prep_w(
    const float* __restrict__ w1e, const float* __restrict__ w2e,
    const float* __restrict__ eembw, const float* __restrict__ w1n,
    const float* __restrict__ w2n, const float* __restrict__ nembw,
    u16* __restrict__ w1et, u16* __restrict__ w2et, u16* __restrict__ eembt,
    u16* __restrict__ w1nt, u16* __restrict__ w2nt, u16* __restrict__ nembt) {
  int i = blockIdx.x * 256 + threadIdx.x;
  if (i < 256 * 352) { int c = i / 352, k = i % 352;
    w1et[i] = (k < 321) ? f2bf(w1e[k * 256 + c]) : (u16)0; return; }
  i -= 256 * 352;
  if (i < 64 * 256) { int c = i / 256, k = i % 256; w2et[i] = f2bf(w2e[k * 64 + c]); return; }
  i -= 64 * 256;
  if (i < 64 * 64) { int c = i / 64, k = i % 64; eembt[i] = f2bf(eembw[k * 64 + c]); return; }
  i -= 64 * 64;
  if (i < 256 * 224) { int c = i / 224, k = i % 224;
    w1nt[i] = (k < 195) ? f2bf(w1n[k * 256 + c]) : (u16)0; return; }
  i -= 256 * 224;
  if (i < 128 * 256) { int c = i / 256, k = i % 256; w2nt[i] = f2bf(w2n[k * 128 + c]); return; }
  i -= 128 * 256;
  if (i < 64 * 128) { int c = i / 128, k = i % 128; nembt[i] = f2bf(nembw[k * 64 + c]); return; }
}

// ---------------- CSR build ----------------
__global__ __launch_bounds__(256) void k_hist(const int* __restrict__ ai,
                                              const int* __restrict__ batch,
                                              int* counts, int* gcounts) {
  int i = blockIdx.x * 256 + threadIdx.x;
  if (i < NEDGES) atomicAdd(&counts[ai[i]], 1);
  if (i < NNODES) atomicAdd(&gcounts[batch[i]], 1);
}

__global__ __launch_bounds__(1024, 1) void k_scan(
    const int* __restrict__ counts, int* __restrict__ offs, int* __restrict__ cursor,
    const int* __restrict__ gcounts, int* __restrict__ goffs) {
  __shared__ int part[1024];
  const int t = threadIdx.x;
  const int* in; int n; int* out; int* cur;
  if (blockIdx.x == 0) { in = counts; n = NNODES; out = offs; cur = cursor; }
  else                 { in = gcounts; n = NGRAPH; out = goffs; cur = nullptr; }
  int chunk = (n + 1023) / 1024;
  long base = (long)t * chunk;
  int s = 0;
  for (int i = 0; i < chunk; ++i) { long j = base + i; if (j < n) s += in[j]; }
  part[t] = s;
  __syncthreads();
  for (int off = 1; off < 1024; off <<= 1) {
    int v = (t >= off) ? part[t - off] : 0;
    __syncthreads();
    part[t] += v;
    __syncthreads();
  }
  int running = part[t] - s;  // exclusive prefix
  for (int i = 0; i < chunk; ++i) {
    long j = base + i;
    if (j < n) { out[j] = running; if (cur) cur[j] = running; running += in[j]; }
  }
  if (t == 1023) out[n] = part[1023];
}

__global__ __launch_bounds__(256) void k_scatter(const int* __restrict__ ai,
                                                 int* cursor, int* __restrict__ csr) {
  int i = blockIdx.x * 256 + threadIdx.x;
  if (i < NEDGES) { int slot = atomicAdd(&cursor[ai[i]], 1); csr[slot] = i; }
}

// ---------------- fused edge kernel ----------------
// 64 edges/block, 4 waves. GEMM1 [64,352]@[352,256] -> relu -> GEMM2 @[256,64]
// -> edge_out (bf16 ws + LDS) -> {coord-MLP e_c -> trans ; GEMM3 @eemb -> edge_emb}
__global__ __launch_bounds__(256, 1) void k_edge(
    const u16* __restrict__ nfbf,
    const int* __restrict__ ai, const int* __restrict__ aj,
    const float* __restrict__ eattr, const float* __restrict__ coords,
    const u16* __restrict__ w1t, const float* __restrict__ b1,
    const u16* __restrict__ w2t, const float* __restrict__ b2,
    const float* __restrict__ cew1, const float* __restrict__ ceb1,
    const float* __restrict__ cew2,
    const u16* __restrict__ eembt, const float* __restrict__ eembb,
    u16* __restrict__ edge_out, float* __restrict__ trans,
    float* __restrict__ edge_emb) {
  __shared__ u16 inh[64 * 352];   // edge_in [64][352]; later h [64][264]
  __shared__ u16 wst[256 * 32];   // w1 K-slice [256 cols][32 k]
  __shared__ u16 w2s[64 * 256];   // w2^T [64 cols][256 k]
  __shared__ u16 eos[64 * 72];    // edge_out tile (stride 72 -> 16B aligned rows)
  __shared__ u16 ees[64 * 64];    // eemb^T
  __shared__ float nrm[64 * 3];
  __shared__ int ail[64], ajl[64];

  const int t = threadIdx.x;
  const int lane = t & 63;
  const int w = t >> 6;
  const int l15 = lane & 15, l4 = lane >> 4;
  const long e0 = (long)blockIdx.x * 64;
  const f32x4 fz = {0.f, 0.f, 0.f, 0.f};

  if (t < 64) {
    long e = e0 + t;
    int a = ai[e], b = aj[e];
    ail[t] = a; ajl[t] = b;
    float dx = coords[a * 3 + 0] - coords[b * 3 + 0];
    float dy = coords[a * 3 + 1] - coords[b * 3 + 1];
    float dz = coords[a * 3 + 2] - coords[b * 3 + 2];
    float rad = dx * dx + dy * dy + dz * dz;
    float inv = 1.0f / (sqrtf(rad) + 1.0f);
    nrm[t * 3 + 0] = dx * inv; nrm[t * 3 + 1] = dy * inv; nrm[t * 3 + 2] = dz * inv;
    inh[t * 352 + 320] = f2bf(rad);
    #pragma unroll
    for (int k = 321; k < 352; ++k) inh[t * 352 + k] = 0;
  }
  for (int c = t; c < 2048; c += 256)
    reinterpret_cast<uint4*>(w2s)[c] = reinterpret_cast<const uint4*>(w2t)[c];
  for (int c = t; c < 512; c += 256)
    reinterpret_cast<uint4*>(ees)[c] = reinterpret_cast<const uint4*>(eembt)[c];
  __syncthreads();

  // gather nf[ai] | nf[aj] (bf16, 16B chunks)
  #pragma unroll
  for (int it = 0; it < 8; ++it) {
    int c = t + it * 256;
    int row = c >> 5, s = (c >> 4) & 1, off = c & 15;
    int node = s ? ajl[row] : ail[row];
    uint4 v = reinterpret_cast<const uint4*>(nfbf + (size_t)node * 128)[off];
    *reinterpret_cast<uint4*>(&inh[row * 352 + s * 128 + off * 8]) = v;
  }
  // edge_attr fp32 -> bf16
  #pragma unroll
  for (int it = 0; it < 2; ++it) {
    int c = t + it * 256;
    int row = c >> 3, u = c & 7;
    const float4* g = reinterpret_cast<const float4*>(eattr + (e0 + row) * 64) + u * 2;
    *reinterpret_cast<uint4*>(&inh[row * 352 + 256 + u * 8]) = pack8(g[0], g[1]);
  }

  // ---- GEMM1: K = 352 in 11 slices, w-slice register double-buffer ----
  f32x4 acc[4][4];
  #pragma unroll
  for (int i = 0; i < 4; ++i)
    #pragma unroll
    for (int j = 0; j < 4; ++j) acc[i][j] = fz;

  uint4 wreg[4];
  #pragma unroll
  for (int i = 0; i < 4; ++i) {
    int c = t + i * 256, col = c >> 2, q = c & 3;
    wreg[i] = *reinterpret_cast<const uint4*>(w1t + col * 352 + q * 8);
  }
  for (int ks = 0; ks < 11; ++ks) {
    __syncthreads();  // staging visible (ks=0) / prev compute done
    #pragma unroll
    for (int i = 0; i < 4; ++i) {
      int c = t + i * 256, col = c >> 2, q = c & 3;
      *reinterpret_cast<uint4*>(&wst[col * 32 + q * 8]) = wreg[i];
    }
    __syncthreads();
    if (ks + 1 < 11) {
      #pragma unroll
      for (int i = 0; i < 4; ++i) {
        int c = t + i * 256, col = c >> 2, q = c & 3;
        wreg[i] = *reinterpret_cast<const uint4*>(w1t + col * 352 + (ks + 1) * 32 + q * 8);
      }
    }
    #pragma unroll
    for (int rf = 0; rf < 4; ++rf) {
      const u16* ap = &inh[(rf * 16 + l15) * 352 + ks * 32 + l4 * 8];
      #pragma unroll
      for (int cf = 0; cf < 4; ++cf) {
        const u16* bp = &wst[(w * 64 + cf * 16 + l15) * 32 + l4 * 8];
        acc[rf][cf] = mfma16(ap, bp, acc[rf][cf]);
      }
    }
  }
  __syncthreads();

  // bias + relu -> h (bf16) into inh reused as [64][264]
  #pragma unroll
  for (int cf = 0; cf < 4; ++cf) {
    int col = w * 64 + cf * 16 + l15;
    float bb = b1[col];
    #pragma unroll
    for (int rf = 0; rf < 4; ++rf)
      #pragma unroll
      for (int r = 0; r < 4; ++r) {
        int row = rf * 16 + l4 * 4 + r;
        inh[row * 264 + col] = f2bf(fmaxf(acc[rf][cf][r] + bb, 0.f));
      }
  }
  __syncthreads();

  // ---- GEMM2: [64,256]@[256,64] ----
  f32x4 acc2[4];
  #pragma unroll
  for (int i = 0; i < 4; ++i) acc2[i] = fz;
  #pragma unroll
  for (int ks = 0; ks < 8; ++ks) {
    const u16* bp = &w2s[(w * 16 + l15) * 256 + ks * 32 + l4 * 8];
    #pragma unroll
    for (int rf = 0; rf < 4; ++rf) {
      const u16* ap = &inh[(rf * 16 + l15) * 264 + ks * 32 + l4 * 8];
      acc2[rf] = mfma16(ap, bp, acc2[rf]);
    }
  }
  {
    int col = w * 16 + l15;
    float bb = b2[col];
    #pragma unroll
    for (int rf = 0; rf < 4; ++rf)
      #pragma unroll
      for (int r = 0; r < 4; ++r) {
        int row = rf * 16 + l4 * 4 + r;
        u16 hv = f2bf(acc2[rf][r] + bb);
        eos[row * 72 + col] = hv;
        edge_out[(e0 + row) * 64 + col] = hv;
      }
  }
  __syncthreads();

  // ---- coord MLP: e_c -> trans ----
  {
    int r = t >> 2, p = t & 3;
    float s0 = 0.f, s1 = 0.f;
    #pragma unroll
    for (int kk = 0; kk < 16; ++kk) {
      int k = p * 16 + kk;
      float v = bf2f(eos[r * 72 + k]);
      s0 = fmaf(v, cew1[k * 2 + 0], s0);
      s1 = fmaf(v, cew1[k * 2 + 1], s1);
    }
    s0 += __shfl_xor(s0, 1); s0 += __shfl_xor(s0, 2);
    s1 += __shfl_xor(s1, 1); s1 += __shfl_xor(s1, 2);
    if (p == 0) {
      float h0 = fmaxf(s0 + ceb1[0], 0.f);
      float h1 = fmaxf(s1 + ceb1[1], 0.f);
      float ec = h0 * cew2[0] + h1 * cew2[1];
      long e = e0 + r;
      trans[e * 3 + 0] = nrm[r * 3 + 0] * ec;
      trans[e * 3 + 1] = nrm[r * 3 + 1] * ec;
      trans[e * 3 + 2] = nrm[r * 3 + 2] * ec;
    }
  }

  // ---- GEMM3: edge_emb = edge_out @ eemb_w + b ----
  f32x4 acc3[4];
  #pragma unroll
  for (int i = 0; i < 4; ++i) acc3[i] = fz;
  #pragma unroll
  for (int ks = 0; ks < 2; ++ks) {
    const u16* bp = &ees[(w * 16 + l15) * 64 + ks * 32 + l4 * 8];
    #pragma unroll
    for (int rf = 0; rf < 4; ++rf) {
      const u16* ap = &eos[(rf * 16 + l15) * 72 + ks * 32 + l4 * 8];
      acc3[rf] = mfma16(ap, bp, acc3[rf]);
    }
  }
  {
    int col = w * 16 + l15;
    float bb = eembb[col];
    #pragma unroll
    for (int rf = 0; rf < 4; ++rf)
      #pragma unroll
      for (int r = 0; r < 4; ++r) {
        int row = rf * 16 + l4 * 4 + r;
        edge_emb[(e0 + row) * 64 + col] = acc3[rf][r] + bb;
      }
  }
}

// ---------------- per-node aggregation + coord_out ----------------
__global__ __launch_bounds__(256) void k_agg(
    const int* __restrict__ offs, const int* __restrict__ csr,
    const u16* __restrict__ edge_out, const float* __restrict__ trans,
    const float* __restrict__ coords, const float* __restrict__ cw,
    const float* __restrict__ cb,
    float* __restrict__ agg, float* __restrict__ coord_out) {
  int n = blockIdx.x * 4 + (threadIdx.x >> 6);
  int lane = threadIdx.x & 63;
  if (n >= NNODES) return;
  int s = offs[n], e = offs[n + 1];
  float acc = 0.f, ts = 0.f;
  for (int i = s; i < e; ++i) {
    int ed = csr[i];
    acc += bf2f(edge_out[(size_t)ed * 64 + lane]);
    if (lane < 3) ts += trans[(size_t)ed * 3 + lane];
  }
  agg[(size_t)n * 64 + lane] = acc;
  float c2 = (lane < 3) ? (coords[n * 3 + lane] + ts) : 0.f;
  float c20 = __shfl(c2, 0), c21 = __shfl(c2, 1), c22 = __shfl(c2, 2);
  if (lane < 3)
    coord_out[n * 3 + lane] =
        cb[lane] + c20 * cw[0 + lane] + c21 * cw[3 + lane] + c22 * cw[6 + lane];
}

// ---------------- fused node MLP kernel ----------------
__global__ __launch_bounds__(256, 1) void k_node(
    const u16* __restrict__ nfbf, const float* __restrict__ agg,
    const float* __restrict__ coord_out,
    const u16* __restrict__ w1t, const float* __restrict__ b1,
    const u16* __restrict__ w2t, const float* __restrict__ b2,
    const u16* __restrict__ nembt, const float* __restrict__ nembb,
    float* __restrict__ node_emb) {
  __shared__ u16 inh[64 * 264];   // node_in [64][224]; later h [64][264]
  __shared__ u16 wst[256 * 32];
  __shared__ u16 w2s[128 * 256];
  __shared__ u16 nos[64 * 136];   // node_out tile
  __shared__ u16 nes[64 * 128];   // nemb^T

  const int t = threadIdx.x;
  const int lane = t & 63;
  const int w = t >> 6;
  const int l15 = lane & 15, l4 = lane >> 4;
  const int n0 = blockIdx.x * 64;
  const f32x4 fz = {0.f, 0.f, 0.f, 0.f};
  const uint4 z4 = make_uint4(0, 0, 0, 0);

  for (int c = t; c < 4096; c += 256)
    reinterpret_cast<uint4*>(w2s)[c] = reinterpret_cast<const uint4*>(w2t)[c];
  for (int c = t; c < 1024; c += 256)
    reinterpret_cast<uint4*>(nes)[c] = reinterpret_cast<const uint4*>(nembt)[c];

  if (t < 64) {
    int n = n0 + t;
    bool valid = n < NNODES;
    #pragma unroll
    for (int j = 0; j < 3; ++j)
      inh[t * 224 + 192 + j] = valid ? f2bf(coord_out[n * 3 + j]) : (u16)0;
    #pragma unroll
    for (int k = 195; k < 224; ++k) inh[t * 224 + k] = 0;
  }
  #pragma unroll
  for (int it = 0; it < 4; ++it) {
    int c = t + it * 256;
    int row = c >> 4, off = c & 15;
    int n = n0 + row;
    uint4 v = (n < NNODES) ? reinterpret_cast<const uint4*>(nfbf + (size_t)n * 128)[off] : z4;
    *reinterpret_cast<uint4*>(&inh[row * 224 + off * 8]) = v;
  }
  #pragma unroll
  for (int it = 0; it < 2; ++it) {
    int c = t + it * 256;
    int row = c >> 3, u = c & 7;
    int n = n0 + row;
    uint4 v = z4;
    if (n < NNODES) {
      const float4* g = reinterpret_cast<const float4*>(agg + (size_t)n * 64) + u * 2;
      v = pack8(g[0], g[1]);
    }
    *reinterpret_cast<uint4*>(&inh[row * 224 + 128 + u * 8]) = v;
  }

  // ---- GEMM1: K = 224 in 7 slices ----
  f32x4 acc[4][4];
  #pragma unroll
  for (int i = 0; i < 4; ++i)
    #pragma unroll
    for (int j = 0; j < 4; ++j) acc[i][j] = fz;

  uint4 wreg[4];
  #pragma unroll
  for (int i = 0; i < 4; ++i) {
    int c = t + i * 256, col = c >> 2, q = c & 3;
    wreg[i] = *reinterpret_cast<const uint4*>(w1t + col * 224 + q * 8);
  }
  for (int ks = 0; ks < 7; ++ks) {
    __syncthreads();
    #pragma unroll
    for (int i = 0; i < 4; ++i) {
      int c = t + i * 256, col = c >> 2, q = c & 3;
      *reinterpret_cast<uint4*>(&wst[col * 32 + q * 8]) = wreg[i];
    }
    __syncthreads();
    if (ks + 1 < 7) {
      #pragma unroll
      for (int i = 0; i < 4; ++i) {
        int c = t + i * 256, col = c >> 2, q = c & 3;
        wreg[i] = *reinterpret_cast<const uint4*>(w1t + col * 224 + (ks + 1) * 32 + q * 8);
      }
    }
    #pragma unroll
    for (int rf = 0; rf < 4; ++rf) {
      const u16* ap = &inh[(rf * 16 + l15) * 224 + ks * 32 + l4 * 8];
      #pragma unroll
      for (int cf = 0; cf < 4; ++cf) {
        const u16* bp = &wst[(w * 64 + cf * 16 + l15) * 32 + l4 * 8];
        acc[rf][cf] = mfma16(ap, bp, acc[rf][cf]);
      }
    }
  }
  __syncthreads();

  #pragma unroll
  for (int cf = 0; cf < 4; ++cf) {
    int col = w * 64 + cf * 16 + l15;
    float bb = b1[col];
    #pragma unroll
    for (int rf = 0; rf < 4; ++rf)
      #pragma unroll
      for (int r = 0; r < 4; ++r) {
        int row = rf * 16 + l4 * 4 + r;
        inh[row * 264 + col] = f2bf(fmaxf(acc[rf][cf][r] + bb, 0.f));
      }
  }
  __syncthreads();

  // ---- GEMM2: [64,256]@[256,128] ----
  f32x4 acc2[4][2];
  #pragma unroll
  for (int i = 0; i < 4; ++i) { acc2[i][0] = fz; acc2[i][1] = fz; }
  #pragma unroll
  for (int ks = 0; ks < 8; ++ks) {
    const u16* bp0 = &w2s[(w * 32 + l15) * 256 + ks * 32 + l4 * 8];
    const u16* bp1 = &w2s[(w * 32 + 16 + l15) * 256 + ks * 32 + l4 * 8];
    #pragma unroll
    for (int rf = 0; rf < 4; ++rf) {
      const u16* ap = &inh[(rf * 16 + l15) * 264 + ks * 32 + l4 * 8];
      acc2[rf][0] = mfma16(ap, bp0, acc2[rf][0]);
      acc2[rf][1] = mfma16(ap, bp1, acc2[rf][1]);
    }
  }
  #pragma unroll
  for (int cf = 0; cf < 2; ++cf) {
    int col = w * 32 + cf * 16 + l15;
    float bb = b2[col];
    #pragma unroll
    for (int rf = 0; rf < 4; ++rf)
      #pragma unroll
      for (int r = 0; r < 4; ++r) {
        int row = rf * 16 + l4 * 4 + r;
        nos[row * 136 + col] = f2bf(acc2[rf][cf][r] + bb);
      }
  }
  __syncthreads();

  // ---- GEMM3: node_emb = node_out @ nemb_w + b ----
  f32x4 acc3[4];
  #pragma unroll
  for (int i = 0; i < 4; ++i) acc3[i] = fz;
  #pragma unroll
  for (int ks = 0; ks < 4; ++ks) {
    const u16* bp = &nes[(w * 16 + l15) * 128 + ks * 32 + l4 * 8];
    #pragma unroll
    for (int rf = 0; rf < 4; ++rf) {
      const u16* ap = &nos[(rf * 16 + l15) * 136 + ks * 32 + l4 * 8];
      acc3[rf] = mfma16(ap, bp, acc3[rf]);
    }
  }
  {
    int col = w * 16 + l15;
    float bb = nembb[col];
    #pragma unroll
    for (int rf = 0; rf < 4; ++rf)
      #pragma unroll
      for (int r = 0; r < 4; ++r) {
        int row = rf * 16 + l4 * 4 + r;
        int n = n0 + row;
        if (n < NNODES) node_emb[(size_t)n * 64 + col] = acc3[rf][r] + bb;
      }
  }
}

// ---------------- graph mean pool ----------------
__global__ __launch_bounds__(64) void k_pool(const int* __restrict__ goffs,
                                             const float* __restrict__ node_emb,
                                             float* __restrict__ graph_emb) {
  int g = blockIdx.x, lane = threadIdx.x;
  int s = goffs[g], e = goffs[g + 1];
  float acc = 0.f;
  for (int n = s; n < e; ++n) acc += node_emb[(size_t)n * 64 + lane];
  graph_emb[g * 64 + lane] = acc / fmaxf((float)(e - s), 1.0f);
}

// ---------------- launch ----------------
extern "C" void kernel_launch(void* const* d_in, const int* in_sizes, int n_in,
                              void* d_out, int out_size, void* d_ws, size_t ws_size,
                              hipStream_t stream) {
  const float* node_feats = (const float*)d_in[0];
  const int* eidx = (const int*)d_in[1];
  const int* ai = eidx;
  const int* aj = eidx + NEDGES;
  const float* eattr = (const float*)d_in[2];
  const float* coords = (const float*)d_in[3];
  const int* batch = (const int*)d_in[4];
  const float* w1e = (const float*)d_in[6];
  const float* b1e = (const float*)d_in[7];
  const float* w2e = (const float*)d_in[8];
  const float* b2e = (const float*)d_in[9];
  const float* w1n = (const float*)d_in[10];
  const float* b1n = (const float*)d_in[11];
  const float* w2n = (const float*)d_in[12];
  const float* b2n = (const float*)d_in[13];
  const float* cew1 = (const float*)d_in[14];
  const float* ceb1 = (const float*)d_in[15];
  const float* cew2 = (const float*)d_in[16];
  const float* cw = (const float*)d_in[17];
  const float* cb = (const float*)d_in[18];
  const float* nembw = (const float*)d_in[19];
  const float* nembb = (const float*)d_in[20];
  const float* eembw = (const float*)d_in[21];
  const float* eembb = (const float*)d_in[22];

  char* ws = (char*)d_ws;
  u16* NFBF = (u16*)(ws + OFF_NFBF);
  u16* W1ET = (u16*)(ws + OFF_W1ET);
  u16* W2ET = (u16*)(ws + OFF_W2ET);
  u16* EEMBT = (u16*)(ws + OFF_EEMBT);
  u16* W1NT = (u16*)(ws + OFF_W1NT);
  u16* W2NT = (u16*)(ws + OFF_W2NT);
  u16* NEMBT = (u16*)(ws + OFF_NEMBT);
  int* COUNTS = (int*)(ws + OFF_COUNTS);
  int* GCNT = (int*)(ws + OFF_GCNT);
  int* OFFS = (int*)(ws + OFF_OFFS);
  int* GOFFS = (int*)(ws + OFF_GOFFS);
  int* CURSOR = (int*)(ws + OFF_CURSOR);
  int* CSR = (int*)(ws + OFF_CSR);
  u16* EOUT = (u16*)(ws + OFF_EOUT);
  float* TRANS = (float*)(ws + OFF_TRANS);
  float* AGG = (float*)(ws + OFF_AGG);

  float* out = (float*)d_out;
  float* o_nemb = out;              // [1e5,64]
  float* o_eemb = out + 6400000;    // [1e6,64]
  float* o_gemb = out + 70400000;   // [512,64]
  float* o_cout = out + 70432768;   // [1e5,3]

  hipMemsetAsync(ws + OFF_COUNTS, 0, 402048, stream);  // COUNTS + GCNT
  k_prep_nf<<<6250, 256, 0, stream>>>(node_feats, NFBF);
  k_prep_w<<<816, 256, 0, stream>>>(w1e, w2e, eembw, w1n, w2n, nembw,
                                    W1ET, W2ET, EEMBT, W1NT, W2NT, NEMBT);
  k_hist<<<3907, 256, 0, stream>>>(ai, batch, COUNTS, GCNT);
  k_scan<<<2, 1024, 0, stream>>>(COUNTS, OFFS, CURSOR, GCNT, GOFFS);
  k_scatter<<<3907, 256, 0, stream>>>(ai, CURSOR, CSR);
  k_edge<<<15625, 256, 0, stream>>>(NFBF, ai, aj, eattr, coords,
                                    W1ET, b1e, W2ET, b2e,
                                    cew1, ceb1, cew2, EEMBT, eembb,
                                    EOUT, TRANS, o_eemb);
  k_agg<<<25000, 256, 0, stream>>>(OFFS, CSR, EOUT, TRANS, coords, cw, cb,
                                   AGG, o_cout);
  k_node<<<1563, 256, 0, stream>>>(NFBF, AGG, o_cout, W1NT, b1n, W2NT, b2n,
                                   NEMBT, nembb, o_nemb);
  k_pool<<<512, 64, 0, stream>>>(GOFFS, o_nemb, o_gemb);
}